// Round 1
// baseline (333.566 us; speedup 1.0000x reference)
//
#include <hip/hip_runtime.h>
#include <hip/hip_bf16.h>

// MultiHeadAttention: B=4, S=2048, D_MODEL=512, N_HEAD=8, D_K=64
// Pipeline: proj_gemm(Q), proj_gemm(K), proj_gemm(V->transposed), flash_attn, out_gemm

typedef __attribute__((ext_vector_type(8))) short short8;
typedef __attribute__((ext_vector_type(4))) float f32x4;
typedef __attribute__((ext_vector_type(4))) unsigned short u16x4;

static __device__ __forceinline__ unsigned short f2bf(float x) {
  union { float f; unsigned u; } v; v.f = x;
  unsigned r = v.u + 0x7fffu + ((v.u >> 16) & 1u);  // round-to-nearest-even
  return (unsigned short)(r >> 16);
}

static __device__ __forceinline__ short8 ld8(const unsigned short* p) {
  return *reinterpret_cast<const short8*>(p);
}

// ---------------------------------------------------------------------------
// Projection GEMM: out = X[8192,512] @ W^T + b, W is [N=512, K=512] row-major
// (so B-operand rows are W[n, k] — B^T-input GEMM). Output bf16 scattered to
// head layout: vmode=0 -> [b*8+h][s][d] ; vmode=1 -> [b*8+h][d][s] (V^T).
// 128x128 tile, BK=32, 256 threads = 4 waves in 2x2, each wave 64x64.
// ---------------------------------------------------------------------------
__global__ __launch_bounds__(256) void proj_gemm(
    const float* __restrict__ X, const float* __restrict__ W,
    const float* __restrict__ bias, unsigned short* __restrict__ dst, int vmode)
{
  __shared__ unsigned short Al[128][40];  // +8 pad: 80B rows, 16B-aligned, 2-way banks (free)
  __shared__ unsigned short Bl[128][40];
  const int tid = threadIdx.x;
  const int lane = tid & 63;
  const int g = lane >> 4, c = lane & 15;
  const int wave = tid >> 6;
  const int m0 = blockIdx.x * 128, n0 = blockIdx.y * 128;
  const int wm = (wave & 1) * 64, wn = (wave >> 1) * 64;
  f32x4 acc[4][4] = {};

  const int srow = tid >> 3;         // 0..31
  const int scol = (tid & 7) * 4;    // 0..28 step 4

  for (int k0 = 0; k0 < 512; k0 += 32) {
    __syncthreads();
#pragma unroll
    for (int p = 0; p < 4; ++p) {
      int row = p * 32 + srow;
      f32x4 xv = *reinterpret_cast<const f32x4*>(&X[(size_t)(m0 + row) * 512 + k0 + scol]);
      u16x4 xb = { f2bf(xv[0]), f2bf(xv[1]), f2bf(xv[2]), f2bf(xv[3]) };
      *reinterpret_cast<u16x4*>(&Al[row][scol]) = xb;
      f32x4 wv = *reinterpret_cast<const f32x4*>(&W[(size_t)(n0 + row) * 512 + k0 + scol]);
      u16x4 wb = { f2bf(wv[0]), f2bf(wv[1]), f2bf(wv[2]), f2bf(wv[3]) };
      *reinterpret_cast<u16x4*>(&Bl[row][scol]) = wb;
    }
    __syncthreads();
    short8 af[4], bfr[4];
#pragma unroll
    for (int i = 0; i < 4; ++i) {
      af[i]  = ld8(&Al[wm + i * 16 + c][g * 8]);
      bfr[i] = ld8(&Bl[wn + i * 16 + c][g * 8]);
    }
#pragma unroll
    for (int i = 0; i < 4; ++i)
#pragma unroll
      for (int j = 0; j < 4; ++j)
        acc[i][j] = __builtin_amdgcn_mfma_f32_16x16x32_bf16(af[i], bfr[j], acc[i][j], 0, 0, 0);
  }

#pragma unroll
  for (int j = 0; j < 4; ++j) {
    int col = n0 + wn + j * 16 + c;        // model dim n
    float bcol = bias[col];
    int h = col >> 6, d = col & 63;
#pragma unroll
    for (int i = 0; i < 4; ++i) {
#pragma unroll
      for (int r = 0; r < 4; ++r) {
        int row = m0 + wm + i * 16 + g * 4 + r;   // flat (b,s)
        int b = row >> 11, s = row & 2047;
        float val = acc[i][j][r] + bcol;
        size_t idx = vmode ? ((size_t)((b * 8 + h) * 64 + d) * 2048 + s)
                           : ((size_t)((b * 8 + h) * 2048 + s) * 64 + d);
        dst[idx] = f2bf(val);
      }
    }
  }
}

// ---------------------------------------------------------------------------
// Flash attention: per (b,h): Q[2048,64] bf16, K[2048,64] bf16, V^T[64,2048] bf16.
// Block = 4 waves, each wave owns 16 Q-rows, iterates KV in tiles of 32 with
// online softmax. Scores via mfma(Qfrag, K^T frag); P transposed to A-layout
// through per-wave LDS; PV via mfma(Pfrag, V^T-sourced B frag).
// ---------------------------------------------------------------------------
__global__ __launch_bounds__(256) void flash_attn(
    const unsigned short* __restrict__ Qh, const unsigned short* __restrict__ Kh,
    const unsigned short* __restrict__ Vt, unsigned short* __restrict__ attn)
{
  __shared__ unsigned short P[4][16][56];  // 112B rows: 16B-aligned, 2-way banks
  const int lane = threadIdx.x & 63;
  const int wave = threadIdx.x >> 6;
  const int g = lane >> 4, c = lane & 15;
  const int bh = blockIdx.y;
  const int q0 = blockIdx.x * 64 + wave * 16;
  const unsigned short* Qp = Qh + (size_t)bh * 2048 * 64;
  const unsigned short* Kp = Kh + (size_t)bh * 2048 * 64;
  const unsigned short* Vp = Vt + (size_t)bh * 64 * 2048;

  // Q fragments (held for whole loop): A-layout row=c, k = 32*half + g*8..+7
  short8 qf0 = ld8(Qp + (size_t)(q0 + c) * 64 + g * 8);
  short8 qf1 = ld8(Qp + (size_t)(q0 + c) * 64 + 32 + g * 8);

  f32x4 o[4] = {};
  float mrun[4] = {-1e30f, -1e30f, -1e30f, -1e30f};
  float lrun[4] = {0.f, 0.f, 0.f, 0.f};

  for (int kv = 0; kv < 2048; kv += 32) {
    // K^T B-fragments: n=kv col (c), k = d = 32*half + g*8..+7  -> K[kcol][d] contiguous
    short8 k00 = ld8(Kp + (size_t)(kv + c) * 64 + g * 8);
    short8 k01 = ld8(Kp + (size_t)(kv + c) * 64 + 32 + g * 8);
    short8 k10 = ld8(Kp + (size_t)(kv + 16 + c) * 64 + g * 8);
    short8 k11 = ld8(Kp + (size_t)(kv + 16 + c) * 64 + 32 + g * 8);
    f32x4 s0 = {}, s1 = {};
    s0 = __builtin_amdgcn_mfma_f32_16x16x32_bf16(qf0, k00, s0, 0, 0, 0);
    s0 = __builtin_amdgcn_mfma_f32_16x16x32_bf16(qf1, k01, s0, 0, 0, 0);
    s1 = __builtin_amdgcn_mfma_f32_16x16x32_bf16(qf0, k10, s1, 0, 0, 0);
    s1 = __builtin_amdgcn_mfma_f32_16x16x32_bf16(qf1, k11, s1, 0, 0, 0);

#pragma unroll
    for (int r = 0; r < 4; ++r) {
      // this lane's scores for q-row (g*4+r): cols c and 16+c of the 32-wide tile
      float a  = s0[r] * 0.125f;   // 1/sqrt(64)
      float bb = s1[r] * 0.125f;
      float mt = fmaxf(a, bb);
      mt = fmaxf(mt, __shfl_xor(mt, 1));
      mt = fmaxf(mt, __shfl_xor(mt, 2));
      mt = fmaxf(mt, __shfl_xor(mt, 4));
      mt = fmaxf(mt, __shfl_xor(mt, 8));
      float mn = fmaxf(mrun[r], mt);
      float alpha = __expf(mrun[r] - mn);
      float p0 = __expf(a - mn);
      float p1 = __expf(bb - mn);
      float ls = p0 + p1;
      ls += __shfl_xor(ls, 1);
      ls += __shfl_xor(ls, 2);
      ls += __shfl_xor(ls, 4);
      ls += __shfl_xor(ls, 8);
      lrun[r] = lrun[r] * alpha + ls;
      mrun[r] = mn;
      o[0][r] *= alpha; o[1][r] *= alpha; o[2][r] *= alpha; o[3][r] *= alpha;
      P[wave][g * 4 + r][c] = f2bf(p0);
      P[wave][g * 4 + r][16 + c] = f2bf(p1);
    }
    // P back in A-layout (wave-synchronous LDS round trip, no barrier needed)
    short8 pf = ld8(&P[wave][c][g * 8]);
#pragma unroll
    for (int n = 0; n < 4; ++n) {
      // V B-fragment: n = d-col (n*16+c), k = kv row -> contiguous in V^T
      short8 vf = ld8(Vp + (size_t)(n * 16 + c) * 2048 + kv + g * 8);
      o[n] = __builtin_amdgcn_mfma_f32_16x16x32_bf16(pf, vf, o[n], 0, 0, 0);
    }
  }

  const int b = bh >> 3, h = bh & 7;
#pragma unroll
  for (int n = 0; n < 4; ++n) {
#pragma unroll
    for (int r = 0; r < 4; ++r) {
      int s = q0 + g * 4 + r;
      int d = n * 16 + c;
      float val = o[n][r] / lrun[r];
      attn[((size_t)(b * 2048 + s)) * 512 + h * 64 + d] = f2bf(val);
    }
  }
}

// ---------------------------------------------------------------------------
// Output projection: out(fp32) = attn(bf16)[8192,512] @ W_o^T + b_o
// ---------------------------------------------------------------------------
__global__ __launch_bounds__(256) void out_gemm(
    const unsigned short* __restrict__ A, const float* __restrict__ W,
    const float* __restrict__ bias, float* __restrict__ out)
{
  __shared__ unsigned short Al[128][40];
  __shared__ unsigned short Bl[128][40];
  const int tid = threadIdx.x;
  const int lane = tid & 63;
  const int g = lane >> 4, c = lane & 15;
  const int wave = tid >> 6;
  const int m0 = blockIdx.x * 128, n0 = blockIdx.y * 128;
  const int wm = (wave & 1) * 64, wn = (wave >> 1) * 64;
  f32x4 acc[4][4] = {};

  const int arow = tid >> 2;         // 0..63
  const int acol = (tid & 3) * 8;    // 0,8,16,24
  const int srow = tid >> 3;
  const int scol = (tid & 7) * 4;

  for (int k0 = 0; k0 < 512; k0 += 32) {
    __syncthreads();
#pragma unroll
    for (int p = 0; p < 2; ++p) {
      int row = p * 64 + arow;
      short8 av = ld8(&A[(size_t)(m0 + row) * 512 + k0 + acol]);
      *reinterpret_cast<short8*>(&Al[row][acol]) = av;
    }
#pragma unroll
    for (int p = 0; p < 4; ++p) {
      int row = p * 32 + srow;
      f32x4 wv = *reinterpret_cast<const f32x4*>(&W[(size_t)(n0 + row) * 512 + k0 + scol]);
      u16x4 wb = { f2bf(wv[0]), f2bf(wv[1]), f2bf(wv[2]), f2bf(wv[3]) };
      *reinterpret_cast<u16x4*>(&Bl[row][scol]) = wb;
    }
    __syncthreads();
    short8 af[4], bfr[4];
#pragma unroll
    for (int i = 0; i < 4; ++i) {
      af[i]  = ld8(&Al[wm + i * 16 + c][g * 8]);
      bfr[i] = ld8(&Bl[wn + i * 16 + c][g * 8]);
    }
#pragma unroll
    for (int i = 0; i < 4; ++i)
#pragma unroll
      for (int j = 0; j < 4; ++j)
        acc[i][j] = __builtin_amdgcn_mfma_f32_16x16x32_bf16(af[i], bfr[j], acc[i][j], 0, 0, 0);
  }

#pragma unroll
  for (int j = 0; j < 4; ++j) {
    int col = n0 + wn + j * 16 + c;
    float bcol = bias[col];
#pragma unroll
    for (int i = 0; i < 4; ++i)
#pragma unroll
      for (int r = 0; r < 4; ++r) {
        int row = m0 + wm + i * 16 + g * 4 + r;
        out[(size_t)row * 512 + col] = acc[i][j][r] + bcol;
      }
  }
}

extern "C" void kernel_launch(void* const* d_in, const int* in_sizes, int n_in,
                              void* d_out, int out_size, void* d_ws, size_t ws_size,
                              hipStream_t stream)
{
  const float* q  = (const float*)d_in[0];
  const float* k  = (const float*)d_in[1];
  const float* v  = (const float*)d_in[2];
  const float* Wq = (const float*)d_in[3];
  const float* bq = (const float*)d_in[4];
  const float* Wk = (const float*)d_in[5];
  const float* bk = (const float*)d_in[6];
  const float* Wv = (const float*)d_in[7];
  const float* bv = (const float*)d_in[8];
  const float* Wo = (const float*)d_in[9];
  const float* bo = (const float*)d_in[10];
  float* out = (float*)d_out;

  // workspace: 4 x 8 MB bf16 buffers (32 MB total)
  unsigned short* ws = (unsigned short*)d_ws;
  unsigned short* Qh = ws;                              // [32][2048][64]
  unsigned short* Kh = ws + (size_t)4 * 1024 * 1024;    // [32][2048][64]
  unsigned short* Vt = ws + (size_t)8 * 1024 * 1024;    // [32][64][2048]
  unsigned short* at = ws + (size_t)12 * 1024 * 1024;   // [4][2048][512]

  dim3 blk(256);
  proj_gemm<<<dim3(64, 4), blk, 0, stream>>>(q, Wq, bq, Qh, 0);
  proj_gemm<<<dim3(64, 4), blk, 0, stream>>>(k, Wk, bk, Kh, 0);
  proj_gemm<<<dim3(64, 4), blk, 0, stream>>>(v, Wv, bv, Vt, 1);
  flash_attn<<<dim3(32, 32), blk, 0, stream>>>(Qh, Kh, Vt, at);
  out_gemm<<<dim3(64, 4), blk, 0, stream>>>(at, Wo, bo, out);
}

// Round 4
// 222.991 us; speedup vs baseline: 1.4959x; 1.4959x over previous
//
#include <hip/hip_runtime.h>
#include <hip/hip_bf16.h>

// MultiHeadAttention: B=4, S=2048, D_MODEL=512, N_HEAD=8, D_K=64
// Pipeline: proj_gemm(Q*scale), proj_gemm(K), proj_gemm(V->transposed), flash_attn, out_gemm

typedef __attribute__((ext_vector_type(8))) short short8;
typedef __attribute__((ext_vector_type(4))) float f32x4;
typedef __attribute__((ext_vector_type(16))) float f32x16;
typedef __attribute__((ext_vector_type(4))) unsigned short u16x4;

static __device__ __forceinline__ unsigned short f2bf(float x) {
  union { float f; unsigned u; } v; v.f = x;
  unsigned r = v.u + 0x7fffu + ((v.u >> 16) & 1u);  // round-to-nearest-even
  return (unsigned short)(r >> 16);
}

static __device__ __forceinline__ short8 ld8(const unsigned short* p) {
  return *reinterpret_cast<const short8*>(p);
}

// ---------------------------------------------------------------------------
// Projection GEMM: out = (X[8192,512] @ W^T + b) * oscale, W row-major [N,K].
// Output bf16 scattered: vmode=0 -> [b*8+h][s][d] ; vmode=1 -> [b*8+h][d][s].
// ---------------------------------------------------------------------------
__global__ __launch_bounds__(256) void proj_gemm(
    const float* __restrict__ X, const float* __restrict__ W,
    const float* __restrict__ bias, unsigned short* __restrict__ dst, int vmode,
    float oscale)
{
  __shared__ unsigned short Al[128][40];
  __shared__ unsigned short Bl[128][40];
  const int tid = threadIdx.x;
  const int lane = tid & 63;
  const int g = lane >> 4, c = lane & 15;
  const int wave = tid >> 6;
  const int m0 = blockIdx.x * 128, n0 = blockIdx.y * 128;
  const int wm = (wave & 1) * 64, wn = (wave >> 1) * 64;
  f32x4 acc[4][4] = {};

  const int srow = tid >> 3;
  const int scol = (tid & 7) * 4;

  for (int k0 = 0; k0 < 512; k0 += 32) {
    __syncthreads();
#pragma unroll
    for (int p = 0; p < 4; ++p) {
      int row = p * 32 + srow;
      f32x4 xv = *reinterpret_cast<const f32x4*>(&X[(size_t)(m0 + row) * 512 + k0 + scol]);
      u16x4 xb = { f2bf(xv[0]), f2bf(xv[1]), f2bf(xv[2]), f2bf(xv[3]) };
      *reinterpret_cast<u16x4*>(&Al[row][scol]) = xb;
      f32x4 wv = *reinterpret_cast<const f32x4*>(&W[(size_t)(n0 + row) * 512 + k0 + scol]);
      u16x4 wb = { f2bf(wv[0]), f2bf(wv[1]), f2bf(wv[2]), f2bf(wv[3]) };
      *reinterpret_cast<u16x4*>(&Bl[row][scol]) = wb;
    }
    __syncthreads();
    short8 af[4], bfr[4];
#pragma unroll
    for (int i = 0; i < 4; ++i) {
      af[i]  = ld8(&Al[wm + i * 16 + c][g * 8]);
      bfr[i] = ld8(&Bl[wn + i * 16 + c][g * 8]);
    }
#pragma unroll
    for (int i = 0; i < 4; ++i)
#pragma unroll
      for (int j = 0; j < 4; ++j)
        acc[i][j] = __builtin_amdgcn_mfma_f32_16x16x32_bf16(af[i], bfr[j], acc[i][j], 0, 0, 0);
  }

#pragma unroll
  for (int j = 0; j < 4; ++j) {
    int col = n0 + wn + j * 16 + c;
    float bcol = bias[col];
    int h = col >> 6, d = col & 63;
#pragma unroll
    for (int i = 0; i < 4; ++i) {
#pragma unroll
      for (int r = 0; r < 4; ++r) {
        int row = m0 + wm + i * 16 + g * 4 + r;
        int b = row >> 11, s = row & 2047;
        float val = (acc[i][j][r] + bcol) * oscale;
        size_t idx = vmode ? ((size_t)((b * 8 + h) * 64 + d) * 2048 + s)
                           : ((size_t)((b * 8 + h) * 2048 + s) * 64 + d);
        dst[idx] = f2bf(val);
      }
    }
  }
}

// ---------------------------------------------------------------------------
// Flash attention, swapped-QK 32x32 structure.
// Per (b,h): Q[2048,64] (pre-scaled by 1/8), K[2048,64], V^T[64,2048], all bf16.
// Block = 4 waves = 2 q-tiles(32 rows) x 2 kv-halves (split-KV, LDS merge).
// Per wave: S^T = mfma(K,Q) -> lane owns q-col (lane&31), 16 kv scores in regs
// at rows r(i,hi)=(i&3)+8*(i>>2)+4*hi (m74/m101-verified C/D layout).
// ALL cross-half exchange via __shfl_xor(x,32) (session-verified primitive;
// permlane32_swap inline asm mis-behaved in rounds 2/3).
// PV: O^T[d][q] += mfma(V^T-frag, P-frag). No LDS in main loop.
// ---------------------------------------------------------------------------
__global__ __launch_bounds__(256) void flash_attn(
    const unsigned short* __restrict__ Qh, const unsigned short* __restrict__ Kh,
    const unsigned short* __restrict__ Vt, unsigned short* __restrict__ attn)
{
  __shared__ float Mred[2][2][32];
  __shared__ float Lred[2][2][32];
  __shared__ float AccO[2][64][32];   // [qtile][d][q] partner partial O
  const int lane = threadIdx.x & 63;
  const int wave = threadIdx.x >> 6;
  const int lq = lane & 31;   // q column within tile
  const int hi = lane >> 5;   // lane half
  const int qt = wave >> 1;   // q-tile within block
  const int kh = wave & 1;    // kv half
  const int bh = blockIdx.y;
  const int q0 = blockIdx.x * 64 + qt * 32;
  const unsigned short* Qp = Qh + (size_t)bh * 2048 * 64;
  const unsigned short* Kp = Kh + (size_t)bh * 2048 * 64;
  const unsigned short* Vp = Vt + (size_t)bh * 64 * 2048;

  // Q B-fragments: col=lq, k=d = ds*16 + hi*8 + j
  short8 qf[4];
#pragma unroll
  for (int ds = 0; ds < 4; ++ds)
    qf[ds] = ld8(Qp + (size_t)(q0 + lq) * 64 + ds * 16 + hi * 8);

  f32x16 acc0 = {}, acc1 = {};
  float mrun = -1e30f, lrun = 0.f;

  const int kv_beg = kh * 1024, kv_end = kv_beg + 1024;
  for (int kv = kv_beg; kv < kv_end; kv += 32) {
    // K A-frags (row=lq of kv tile, k=d) and V^T A-frags (row=d, k=kv)
    short8 kf0 = ld8(Kp + (size_t)(kv + lq) * 64 +  0 + hi * 8);
    short8 kf1 = ld8(Kp + (size_t)(kv + lq) * 64 + 16 + hi * 8);
    short8 kf2 = ld8(Kp + (size_t)(kv + lq) * 64 + 32 + hi * 8);
    short8 kf3 = ld8(Kp + (size_t)(kv + lq) * 64 + 48 + hi * 8);
    short8 vf00 = ld8(Vp + (size_t)lq * 2048        + kv +  0 + hi * 8);
    short8 vf01 = ld8(Vp + (size_t)(32 + lq) * 2048 + kv +  0 + hi * 8);
    short8 vf10 = ld8(Vp + (size_t)lq * 2048        + kv + 16 + hi * 8);
    short8 vf11 = ld8(Vp + (size_t)(32 + lq) * 2048 + kv + 16 + hi * 8);

    f32x16 sp = {};
    sp = __builtin_amdgcn_mfma_f32_32x32x16_bf16(kf0, qf[0], sp, 0, 0, 0);
    sp = __builtin_amdgcn_mfma_f32_32x32x16_bf16(kf1, qf[1], sp, 0, 0, 0);
    sp = __builtin_amdgcn_mfma_f32_32x32x16_bf16(kf2, qf[2], sp, 0, 0, 0);
    sp = __builtin_amdgcn_mfma_f32_32x32x16_bf16(kf3, qf[3], sp, 0, 0, 0);

    // ---- online softmax: lane-local over 16 regs + one cross-half shfl ----
    float tm = sp[0];
#pragma unroll
    for (int i = 1; i < 16; ++i) tm = fmaxf(tm, sp[i]);
    float tmx = fmaxf(tm, __shfl_xor(tm, 32));
    // unconditional rescale this round (defer-max re-added once verified)
    float mn = fmaxf(mrun, tmx);
    float alpha = __expf(mrun - mn);
    mrun = mn;
    lrun *= alpha;
#pragma unroll
    for (int i = 0; i < 16; ++i) { acc0[i] *= alpha; acc1[i] *= alpha; }

    float p[16];
    float ls = 0.f;
#pragma unroll
    for (int i = 0; i < 16; ++i) { p[i] = __expf(sp[i] - mrun); ls += p[i]; }
    lrun += ls + __shfl_xor(ls, 32);

    // ---- P -> bf16 B-fragments via shfl_xor(32) + select ----
    // pk[i] = (p[2i],p[2i+1]) = P rows (r(2i,hi), r(2i+1,hi)), 2-aligned pairs:
    //   pk0=(4hi,4hi+1) pk1=(4hi+2,4hi+3) pk2=(8+4hi,8+4hi+1) pk3=(10+4hi,11+4hi)
    //   pk4..7 same +16.
    // B-frag word w needs rows (8hi+2w, 8hi+2w+1)  [pf0], +16 [pf1].
    int pk[8];
#pragma unroll
    for (int i = 0; i < 8; ++i)
      asm("v_cvt_pk_bf16_f32 %0, %1, %2" : "=v"(pk[i]) : "v"(p[2 * i]), "v"(p[2 * i + 1]));
    int x0 = __shfl_xor(pk[0], 32), x1 = __shfl_xor(pk[1], 32);
    int x2 = __shfl_xor(pk[2], 32), x3 = __shfl_xor(pk[3], 32);
    int x4 = __shfl_xor(pk[4], 32), x5 = __shfl_xor(pk[5], 32);
    int x6 = __shfl_xor(pk[6], 32), x7 = __shfl_xor(pk[7], 32);
    union { int w[4]; short8 v; } pf0, pf1;
    pf0.w[0] = hi ? x2 : pk[0];   // hi0:(0,1)   hi1:(8,9)
    pf0.w[1] = hi ? x3 : pk[1];   // hi0:(2,3)   hi1:(10,11)
    pf0.w[2] = hi ? pk[2] : x0;   // hi0:(4,5)   hi1:(12,13)
    pf0.w[3] = hi ? pk[3] : x1;   // hi0:(6,7)   hi1:(14,15)
    pf1.w[0] = hi ? x6 : pk[4];   // hi0:(16,17) hi1:(24,25)
    pf1.w[1] = hi ? x7 : pk[5];
    pf1.w[2] = hi ? pk[6] : x4;   // hi0:(20,21) hi1:(28,29)
    pf1.w[3] = hi ? pk[7] : x5;

    acc0 = __builtin_amdgcn_mfma_f32_32x32x16_bf16(vf00, pf0.v, acc0, 0, 0, 0);
    acc1 = __builtin_amdgcn_mfma_f32_32x32x16_bf16(vf01, pf0.v, acc1, 0, 0, 0);
    acc0 = __builtin_amdgcn_mfma_f32_32x32x16_bf16(vf10, pf1.v, acc0, 0, 0, 0);
    acc1 = __builtin_amdgcn_mfma_f32_32x32x16_bf16(vf11, pf1.v, acc1, 0, 0, 0);
  }

  // ---- split-KV merge between paired waves (kh 0 <-> 1) ----
  if (lane < 32) { Mred[qt][kh][lq] = mrun; Lred[qt][kh][lq] = lrun; }
  __syncthreads();
  float mo = Mred[qt][kh ^ 1][lq];
  float lo_ = Lred[qt][kh ^ 1][lq];
  float mmax = fmaxf(mrun, mo);
  float sc = __expf(mrun - mmax);
  float so = __expf(mo - mmax);
  float ltot = lrun * sc + lo_ * so;
#pragma unroll
  for (int i = 0; i < 16; ++i) { acc0[i] *= sc; acc1[i] *= sc; }
  if (kh == 1) {
#pragma unroll
    for (int i = 0; i < 16; ++i) {
      int d = (i & 3) + 8 * (i >> 2) + 4 * hi;
      AccO[qt][d][lq]      = acc0[i];
      AccO[qt][32 + d][lq] = acc1[i];
    }
  }
  __syncthreads();
  if (kh == 0) {
    float rl = 1.0f / ltot;
    const int b = bh >> 3, h = bh & 7;
    unsigned short* base = attn + ((size_t)(b * 2048 + q0 + lq)) * 512 + h * 64;
#pragma unroll
    for (int dblk = 0; dblk < 2; ++dblk) {
#pragma unroll
      for (int rq = 0; rq < 4; ++rq) {
        u16x4 o4;
#pragma unroll
        for (int i = 0; i < 4; ++i) {
          int r = rq * 4 + i;
          int d = dblk * 32 + (r & 3) + 8 * (r >> 2) + 4 * hi;
          float own = dblk ? acc1[r] : acc0[r];
          o4[i] = f2bf((own + AccO[qt][d][lq]) * rl);
        }
        *reinterpret_cast<u16x4*>(base + dblk * 32 + rq * 8 + hi * 4) = o4;
      }
    }
  }
}

// ---------------------------------------------------------------------------
// Output projection: out(fp32) = attn(bf16)[8192,512] @ W_o^T + b_o
// ---------------------------------------------------------------------------
__global__ __launch_bounds__(256) void out_gemm(
    const unsigned short* __restrict__ A, const float* __restrict__ W,
    const float* __restrict__ bias, float* __restrict__ out)
{
  __shared__ unsigned short Al[128][40];
  __shared__ unsigned short Bl[128][40];
  const int tid = threadIdx.x;
  const int lane = tid & 63;
  const int g = lane >> 4, c = lane & 15;
  const int wave = tid >> 6;
  const int m0 = blockIdx.x * 128, n0 = blockIdx.y * 128;
  const int wm = (wave & 1) * 64, wn = (wave >> 1) * 64;
  f32x4 acc[4][4] = {};

  const int arow = tid >> 2;
  const int acol = (tid & 3) * 8;
  const int srow = tid >> 3;
  const int scol = (tid & 7) * 4;

  for (int k0 = 0; k0 < 512; k0 += 32) {
    __syncthreads();
#pragma unroll
    for (int p = 0; p < 2; ++p) {
      int row = p * 64 + arow;
      short8 av = ld8(&A[(size_t)(m0 + row) * 512 + k0 + acol]);
      *reinterpret_cast<short8*>(&Al[row][acol]) = av;
    }
#pragma unroll
    for (int p = 0; p < 4; ++p) {
      int row = p * 32 + srow;
      f32x4 wv = *reinterpret_cast<const f32x4*>(&W[(size_t)(n0 + row) * 512 + k0 + scol]);
      u16x4 wb = { f2bf(wv[0]), f2bf(wv[1]), f2bf(wv[2]), f2bf(wv[3]) };
      *reinterpret_cast<u16x4*>(&Bl[row][scol]) = wb;
    }
    __syncthreads();
    short8 af[4], bfr[4];
#pragma unroll
    for (int i = 0; i < 4; ++i) {
      af[i]  = ld8(&Al[wm + i * 16 + c][g * 8]);
      bfr[i] = ld8(&Bl[wn + i * 16 + c][g * 8]);
    }
#pragma unroll
    for (int i = 0; i < 4; ++i)
#pragma unroll
      for (int j = 0; j < 4; ++j)
        acc[i][j] = __builtin_amdgcn_mfma_f32_16x16x32_bf16(af[i], bfr[j], acc[i][j], 0, 0, 0);
  }

#pragma unroll
  for (int j = 0; j < 4; ++j) {
    int col = n0 + wn + j * 16 + c;
    float bcol = bias[col];
#pragma unroll
    for (int i = 0; i < 4; ++i)
#pragma unroll
      for (int r = 0; r < 4; ++r) {
        int row = m0 + wm + i * 16 + g * 4 + r;
        out[(size_t)row * 512 + col] = acc[i][j][r] + bcol;
      }
  }
}

extern "C" void kernel_launch(void* const* d_in, const int* in_sizes, int n_in,
                              void* d_out, int out_size, void* d_ws, size_t ws_size,
                              hipStream_t stream)
{
  const float* q  = (const float*)d_in[0];
  const float* k  = (const float*)d_in[1];
  const float* v  = (const float*)d_in[2];
  const float* Wq = (const float*)d_in[3];
  const float* bq = (const float*)d_in[4];
  const float* Wk = (const float*)d_in[5];
  const float* bk = (const float*)d_in[6];
  const float* Wv = (const float*)d_in[7];
  const float* bv = (const float*)d_in[8];
  const float* Wo = (const float*)d_in[9];
  const float* bo = (const float*)d_in[10];
  float* out = (float*)d_out;

  unsigned short* ws = (unsigned short*)d_ws;
  unsigned short* Qh = ws;                              // [32][2048][64] (pre-scaled 1/8)
  unsigned short* Kh = ws + (size_t)4 * 1024 * 1024;    // [32][2048][64]
  unsigned short* Vt = ws + (size_t)8 * 1024 * 1024;    // [32][64][2048]
  unsigned short* at = ws + (size_t)12 * 1024 * 1024;   // [4][2048][512]

  dim3 blk(256);
  proj_gemm<<<dim3(64, 4), blk, 0, stream>>>(q, Wq, bq, Qh, 0, 0.125f);
  proj_gemm<<<dim3(64, 4), blk, 0, stream>>>(k, Wk, bk, Kh, 0, 1.0f);
  proj_gemm<<<dim3(64, 4), blk, 0, stream>>>(v, Wv, bv, Vt, 1, 1.0f);
  flash_attn<<<dim3(32, 32), blk, 0, stream>>>(Qh, Kh, Vt, at);
  out_gemm<<<dim3(64, 4), blk, 0, stream>>>(at, Wo, bo, out);
}

// Round 5
// 197.456 us; speedup vs baseline: 1.6893x; 1.1293x over previous
//
#include <hip/hip_runtime.h>
#include <hip/hip_bf16.h>

// MultiHeadAttention: B=4, S=2048, D_MODEL=512, N_HEAD=8, D_K=64
// Pipeline: proj3 (Q*log2e/8, K, V->transposed fused), flash_attn (4-way KV split), out_gemm

typedef __attribute__((ext_vector_type(8))) short short8;
typedef __attribute__((ext_vector_type(4))) float f32x4;
typedef __attribute__((ext_vector_type(16))) float f32x16;
typedef __attribute__((ext_vector_type(4))) unsigned short u16x4;

static __device__ __forceinline__ unsigned short f2bf(float x) {
  union { float f; unsigned u; } v; v.f = x;
  unsigned r = v.u + 0x7fffu + ((v.u >> 16) & 1u);  // round-to-nearest-even
  return (unsigned short)(r >> 16);
}

static __device__ __forceinline__ short8 ld8(const unsigned short* p) {
  return *reinterpret_cast<const short8*>(p);
}

static __device__ __forceinline__ float vmax3(float a, float b, float c) {
  float r; asm("v_max3_f32 %0, %1, %2, %3" : "=v"(r) : "v"(a), "v"(b), "v"(c)); return r;
}

static __device__ __forceinline__ float vexp2(float x) {
  float r; asm("v_exp_f32 %0, %1" : "=v"(r) : "v"(x)); return r;
}

// ---------------------------------------------------------------------------
// Fused projection GEMMs: z = blockIdx.z selects {Q, K, V}.
// out = (X[8192,512] @ W^T + b) * oscale, bf16 scatter to head layout.
// Q gets oscale = (1/8)*log2(e) so flash softmax can use exp2 directly.
// V (z==2) written transposed [b*8+h][d][s].
// ---------------------------------------------------------------------------
__global__ __launch_bounds__(256) void proj3(
    const float* __restrict__ Xq, const float* __restrict__ Xk, const float* __restrict__ Xv,
    const float* __restrict__ Wq, const float* __restrict__ Wk, const float* __restrict__ Wv,
    const float* __restrict__ bq, const float* __restrict__ bk, const float* __restrict__ bv,
    unsigned short* __restrict__ Qh, unsigned short* __restrict__ Kh,
    unsigned short* __restrict__ Vt)
{
  const int z = blockIdx.z;
  const float* X = z == 0 ? Xq : z == 1 ? Xk : Xv;
  const float* W = z == 0 ? Wq : z == 1 ? Wk : Wv;
  const float* bias = z == 0 ? bq : z == 1 ? bk : bv;
  unsigned short* dst = z == 0 ? Qh : z == 1 ? Kh : Vt;
  const int vmode = (z == 2);
  const float oscale = z == 0 ? 0.1803368801f : 1.0f;  // (1/8)*log2(e)

  __shared__ unsigned short Al[128][40];
  __shared__ unsigned short Bl[128][40];
  const int tid = threadIdx.x;
  const int lane = tid & 63;
  const int g = lane >> 4, c = lane & 15;
  const int wave = tid >> 6;
  const int m0 = blockIdx.x * 128, n0 = blockIdx.y * 128;
  const int wm = (wave & 1) * 64, wn = (wave >> 1) * 64;
  f32x4 acc[4][4] = {};

  const int srow = tid >> 3;
  const int scol = (tid & 7) * 4;

  for (int k0 = 0; k0 < 512; k0 += 32) {
    __syncthreads();
#pragma unroll
    for (int p = 0; p < 4; ++p) {
      int row = p * 32 + srow;
      f32x4 xv = *reinterpret_cast<const f32x4*>(&X[(size_t)(m0 + row) * 512 + k0 + scol]);
      u16x4 xb = { f2bf(xv[0]), f2bf(xv[1]), f2bf(xv[2]), f2bf(xv[3]) };
      *reinterpret_cast<u16x4*>(&Al[row][scol]) = xb;
      f32x4 wv = *reinterpret_cast<const f32x4*>(&W[(size_t)(n0 + row) * 512 + k0 + scol]);
      u16x4 wb = { f2bf(wv[0]), f2bf(wv[1]), f2bf(wv[2]), f2bf(wv[3]) };
      *reinterpret_cast<u16x4*>(&Bl[row][scol]) = wb;
    }
    __syncthreads();
    short8 af[4], bfr[4];
#pragma unroll
    for (int i = 0; i < 4; ++i) {
      af[i]  = ld8(&Al[wm + i * 16 + c][g * 8]);
      bfr[i] = ld8(&Bl[wn + i * 16 + c][g * 8]);
    }
#pragma unroll
    for (int i = 0; i < 4; ++i)
#pragma unroll
      for (int j = 0; j < 4; ++j)
        acc[i][j] = __builtin_amdgcn_mfma_f32_16x16x32_bf16(af[i], bfr[j], acc[i][j], 0, 0, 0);
  }

#pragma unroll
  for (int j = 0; j < 4; ++j) {
    int col = n0 + wn + j * 16 + c;
    float bcol = bias[col];
    int h = col >> 6, d = col & 63;
#pragma unroll
    for (int i = 0; i < 4; ++i) {
#pragma unroll
      for (int r = 0; r < 4; ++r) {
        int row = m0 + wm + i * 16 + g * 4 + r;
        int b = row >> 11, s = row & 2047;
        float val = (acc[i][j][r] + bcol) * oscale;
        size_t idx = vmode ? ((size_t)((b * 8 + h) * 64 + d) * 2048 + s)
                           : ((size_t)((b * 8 + h) * 2048 + s) * 64 + d);
        dst[idx] = f2bf(val);
      }
    }
  }
}

// ---------------------------------------------------------------------------
// Flash attention, swapped-QK 32x32, 4-way KV split.
// Block = 4 waves, ONE q-tile (32 rows), wave kh owns kv quarter [kh*512, +512).
// Scores in log2 domain (Q pre-scaled by log2e/8): P = exp2(S - m).
// Per wave: S^T = mfma(K,Q), lane owns q-col lq, 16 kv scores in regs at rows
// r(i,hi)=(i&3)+8*(i>>2)+4*hi. Cross-half exchange via __shfl_xor(32)
// (verified r4). Defer-max THR=11 (log2 units) skips most rescales.
// Merge: staged LDS accumulate (waves 2,3 deposit; 0,1 add; 0,1 write out).
// ---------------------------------------------------------------------------
__global__ __launch_bounds__(256) void flash_attn(
    const unsigned short* __restrict__ Qh, const unsigned short* __restrict__ Kh,
    const unsigned short* __restrict__ Vt, unsigned short* __restrict__ attn)
{
  __shared__ float Mred[4][32];
  __shared__ float Lred[4][32];
  __shared__ float AccO[2][64][32];   // [stage][d][q]
  const int lane = threadIdx.x & 63;
  const int kh = threadIdx.x >> 6;    // kv quarter
  const int lq = lane & 31;           // q column within tile
  const int hi = lane >> 5;           // lane half
  const int bh = blockIdx.y;
  const int q0 = blockIdx.x * 32;
  const unsigned short* Qp = Qh + (size_t)bh * 2048 * 64;
  const unsigned short* Kp = Kh + (size_t)bh * 2048 * 64;
  const unsigned short* Vp = Vt + (size_t)bh * 64 * 2048;

  // Q B-fragments: col=lq, k=d = ds*16 + hi*8 + j (same for all 4 waves)
  short8 qf[4];
#pragma unroll
  for (int ds = 0; ds < 4; ++ds)
    qf[ds] = ld8(Qp + (size_t)(q0 + lq) * 64 + ds * 16 + hi * 8);

  f32x16 acc0 = {}, acc1 = {};
  float mrun = -1e30f, lrun = 0.f;

  const int kv_beg = kh * 512, kv_end = kv_beg + 512;
  for (int kv = kv_beg; kv < kv_end; kv += 32) {
    short8 kf0 = ld8(Kp + (size_t)(kv + lq) * 64 +  0 + hi * 8);
    short8 kf1 = ld8(Kp + (size_t)(kv + lq) * 64 + 16 + hi * 8);
    short8 kf2 = ld8(Kp + (size_t)(kv + lq) * 64 + 32 + hi * 8);
    short8 kf3 = ld8(Kp + (size_t)(kv + lq) * 64 + 48 + hi * 8);
    short8 vf00 = ld8(Vp + (size_t)lq * 2048        + kv +  0 + hi * 8);
    short8 vf01 = ld8(Vp + (size_t)(32 + lq) * 2048 + kv +  0 + hi * 8);
    short8 vf10 = ld8(Vp + (size_t)lq * 2048        + kv + 16 + hi * 8);
    short8 vf11 = ld8(Vp + (size_t)(32 + lq) * 2048 + kv + 16 + hi * 8);

    f32x16 sp = {};
    sp = __builtin_amdgcn_mfma_f32_32x32x16_bf16(kf0, qf[0], sp, 0, 0, 0);
    sp = __builtin_amdgcn_mfma_f32_32x32x16_bf16(kf1, qf[1], sp, 0, 0, 0);
    sp = __builtin_amdgcn_mfma_f32_32x32x16_bf16(kf2, qf[2], sp, 0, 0, 0);
    sp = __builtin_amdgcn_mfma_f32_32x32x16_bf16(kf3, qf[3], sp, 0, 0, 0);

    // ---- online softmax (log2 domain), max3 tree + one cross-half shfl ----
    float ta = vmax3(sp[0], sp[1], sp[2]);
    ta = vmax3(ta, sp[3], sp[4]);
    ta = vmax3(ta, sp[5], sp[6]);
    float tb = vmax3(sp[7], sp[8], sp[9]);
    tb = vmax3(tb, sp[10], sp[11]);
    tb = vmax3(tb, sp[12], sp[13]);
    float tm = vmax3(ta, tb, sp[14]);
    tm = fmaxf(tm, sp[15]);
    float tmx = fmaxf(tm, __shfl_xor(tm, 32));
    if (!__all(tmx <= mrun + 11.0f)) {   // defer-max: P bounded by 2^11
      float mn = fmaxf(mrun, tmx);
      float alpha = vexp2(mrun - mn);
      mrun = mn;
      lrun *= alpha;
#pragma unroll
      for (int i = 0; i < 16; ++i) { acc0[i] *= alpha; acc1[i] *= alpha; }
    }
    float p[16];
    float ls = 0.f;
#pragma unroll
    for (int i = 0; i < 16; ++i) { p[i] = vexp2(sp[i] - mrun); ls += p[i]; }
    lrun += ls + __shfl_xor(ls, 32);

    // ---- P -> bf16 B-fragments via shfl_xor(32) + select (verified r4) ----
    int pk[8];
#pragma unroll
    for (int i = 0; i < 8; ++i)
      asm("v_cvt_pk_bf16_f32 %0, %1, %2" : "=v"(pk[i]) : "v"(p[2 * i]), "v"(p[2 * i + 1]));
    int x0 = __shfl_xor(pk[0], 32), x1 = __shfl_xor(pk[1], 32);
    int x2 = __shfl_xor(pk[2], 32), x3 = __shfl_xor(pk[3], 32);
    int x4 = __shfl_xor(pk[4], 32), x5 = __shfl_xor(pk[5], 32);
    int x6 = __shfl_xor(pk[6], 32), x7 = __shfl_xor(pk[7], 32);
    union { int w[4]; short8 v; } pf0, pf1;
    pf0.w[0] = hi ? x2 : pk[0];
    pf0.w[1] = hi ? x3 : pk[1];
    pf0.w[2] = hi ? pk[2] : x0;
    pf0.w[3] = hi ? pk[3] : x1;
    pf1.w[0] = hi ? x6 : pk[4];
    pf1.w[1] = hi ? x7 : pk[5];
    pf1.w[2] = hi ? pk[6] : x4;
    pf1.w[3] = hi ? pk[7] : x5;

    acc0 = __builtin_amdgcn_mfma_f32_32x32x16_bf16(vf00, pf0.v, acc0, 0, 0, 0);
    acc1 = __builtin_amdgcn_mfma_f32_32x32x16_bf16(vf01, pf0.v, acc1, 0, 0, 0);
    acc0 = __builtin_amdgcn_mfma_f32_32x32x16_bf16(vf10, pf1.v, acc0, 0, 0, 0);
    acc1 = __builtin_amdgcn_mfma_f32_32x32x16_bf16(vf11, pf1.v, acc1, 0, 0, 0);
  }

  // ---- 4-way merge via staged LDS accumulate ----
  if (lane < 32) { Mred[kh][lq] = mrun; Lred[kh][lq] = lrun; }
  __syncthreads();
  float m = fmaxf(fmaxf(Mred[0][lq], Mred[1][lq]), fmaxf(Mred[2][lq], Mred[3][lq]));
  float ltot = Lred[0][lq] * vexp2(Mred[0][lq] - m)
             + Lred[1][lq] * vexp2(Mred[1][lq] - m)
             + Lred[2][lq] * vexp2(Mred[2][lq] - m)
             + Lred[3][lq] * vexp2(Mred[3][lq] - m);
  float sc = vexp2(mrun - m);
#pragma unroll
  for (int i = 0; i < 16; ++i) { acc0[i] *= sc; acc1[i] *= sc; }
  if (kh >= 2) {
#pragma unroll
    for (int i = 0; i < 16; ++i) {
      int d = (i & 3) + 8 * (i >> 2) + 4 * hi;
      AccO[kh - 2][d][lq]      = acc0[i];
      AccO[kh - 2][32 + d][lq] = acc1[i];
    }
  }
  __syncthreads();
  if (kh < 2) {
#pragma unroll
    for (int i = 0; i < 16; ++i) {
      int d = (i & 3) + 8 * (i >> 2) + 4 * hi;
      AccO[kh][d][lq]      += acc0[i];
      AccO[kh][32 + d][lq] += acc1[i];
    }
  }
  __syncthreads();
  if (kh < 2) {
    float rl = 1.0f / ltot;
    const int b = bh >> 3, h = bh & 7;
    unsigned short* base = attn + ((size_t)(b * 2048 + q0 + lq)) * 512 + h * 64
                         + kh * 32 + hi * 16;
    union { unsigned short u[16]; short8 v[2]; } ov;
#pragma unroll
    for (int dd = 0; dd < 16; ++dd) {
      int d = kh * 32 + hi * 16 + dd;
      ov.u[dd] = f2bf((AccO[0][d][lq] + AccO[1][d][lq]) * rl);
    }
    *reinterpret_cast<short8*>(base) = ov.v[0];
    *reinterpret_cast<short8*>(base + 8) = ov.v[1];
  }
}

// ---------------------------------------------------------------------------
// Output projection: out(fp32) = attn(bf16)[8192,512] @ W_o^T + b_o
// ---------------------------------------------------------------------------
__global__ __launch_bounds__(256) void out_gemm(
    const unsigned short* __restrict__ A, const float* __restrict__ W,
    const float* __restrict__ bias, float* __restrict__ out)
{
  __shared__ unsigned short Al[128][40];
  __shared__ unsigned short Bl[128][40];
  const int tid = threadIdx.x;
  const int lane = tid & 63;
  const int g = lane >> 4, c = lane & 15;
  const int wave = tid >> 6;
  const int m0 = blockIdx.x * 128, n0 = blockIdx.y * 128;
  const int wm = (wave & 1) * 64, wn = (wave >> 1) * 64;
  f32x4 acc[4][4] = {};

  const int arow = tid >> 2;
  const int acol = (tid & 3) * 8;
  const int srow = tid >> 3;
  const int scol = (tid & 7) * 4;

  for (int k0 = 0; k0 < 512; k0 += 32) {
    __syncthreads();
#pragma unroll
    for (int p = 0; p < 2; ++p) {
      int row = p * 64 + arow;
      short8 av = ld8(&A[(size_t)(m0 + row) * 512 + k0 + acol]);
      *reinterpret_cast<short8*>(&Al[row][acol]) = av;
    }
#pragma unroll
    for (int p = 0; p < 4; ++p) {
      int row = p * 32 + srow;
      f32x4 wv = *reinterpret_cast<const f32x4*>(&W[(size_t)(n0 + row) * 512 + k0 + scol]);
      u16x4 wb = { f2bf(wv[0]), f2bf(wv[1]), f2bf(wv[2]), f2bf(wv[3]) };
      *reinterpret_cast<u16x4*>(&Bl[row][scol]) = wb;
    }
    __syncthreads();
    short8 af[4], bfr[4];
#pragma unroll
    for (int i = 0; i < 4; ++i) {
      af[i]  = ld8(&Al[wm + i * 16 + c][g * 8]);
      bfr[i] = ld8(&Bl[wn + i * 16 + c][g * 8]);
    }
#pragma unroll
    for (int i = 0; i < 4; ++i)
#pragma unroll
      for (int j = 0; j < 4; ++j)
        acc[i][j] = __builtin_amdgcn_mfma_f32_16x16x32_bf16(af[i], bfr[j], acc[i][j], 0, 0, 0);
  }

#pragma unroll
  for (int j = 0; j < 4; ++j) {
    int col = n0 + wn + j * 16 + c;
    float bcol = bias[col];
#pragma unroll
    for (int i = 0; i < 4; ++i)
#pragma unroll
      for (int r = 0; r < 4; ++r) {
        int row = m0 + wm + i * 16 + g * 4 + r;
        out[(size_t)row * 512 + col] = acc[i][j][r] + bcol;
      }
  }
}

extern "C" void kernel_launch(void* const* d_in, const int* in_sizes, int n_in,
                              void* d_out, int out_size, void* d_ws, size_t ws_size,
                              hipStream_t stream)
{
  const float* q  = (const float*)d_in[0];
  const float* k  = (const float*)d_in[1];
  const float* v  = (const float*)d_in[2];
  const float* Wq = (const float*)d_in[3];
  const float* bq = (const float*)d_in[4];
  const float* Wk = (const float*)d_in[5];
  const float* bk = (const float*)d_in[6];
  const float* Wv = (const float*)d_in[7];
  const float* bv = (const float*)d_in[8];
  const float* Wo = (const float*)d_in[9];
  const float* bo = (const float*)d_in[10];
  float* out = (float*)d_out;

  unsigned short* ws = (unsigned short*)d_ws;
  unsigned short* Qh = ws;                              // [32][2048][64] (pre-scaled log2e/8)
  unsigned short* Kh = ws + (size_t)4 * 1024 * 1024;    // [32][2048][64]
  unsigned short* Vt = ws + (size_t)8 * 1024 * 1024;    // [32][64][2048]
  unsigned short* at = ws + (size_t)12 * 1024 * 1024;   // [4][2048][512]

  dim3 blk(256);
  proj3<<<dim3(64, 4, 3), blk, 0, stream>>>(q, k, v, Wq, Wk, Wv, bq, bk, bv, Qh, Kh, Vt);
  flash_attn<<<dim3(64, 32), blk, 0, stream>>>(Qh, Kh, Vt, at);
  out_gemm<<<dim3(64, 4), blk, 0, stream>>>(at, Wo, bo, out);
}